// Round 4
// baseline (183.667 us; speedup 1.0000x reference)
//
#include <hip/hip_runtime.h>

// Problem constants (B=8, C=64, H=128, W=256)
#define HW_ 32768          // H*W
#define OUTHALF 16777216ULL
#define SMEM_BYTES 68608

typedef short short8  __attribute__((ext_vector_type(8)));
typedef short short4v __attribute__((ext_vector_type(4)));
typedef float f32x4   __attribute__((ext_vector_type(4)));

__device__ __forceinline__ unsigned short f2bf(float f) {
  unsigned u = __builtin_bit_cast(unsigned, f);
  u += 0x7fffu + ((u >> 16) & 1u);          // RNE; inputs are finite
  return (unsigned short)(u >> 16);
}
__device__ __forceinline__ float bf2f(short s) {
  unsigned u = ((unsigned)(unsigned short)s) << 16;
  return __builtin_bit_cast(float, u);
}
__device__ __forceinline__ char* swz(char* base, int row, int colByte) {
  // 128-byte rows; XOR-swizzle kills stride-128 bank conflicts
  return base + row * 128 + (colByte ^ ((row & 7) << 4));
}
__device__ __forceinline__ char* swzQ(char* base, int row, int colByte) {
  // 64-byte rows (per-wave scratch)
  return base + row * 64 + (colByte ^ ((row & 3) << 4));
}
__device__ __forceinline__ f32x4 zero4() { f32x4 z = {0.f, 0.f, 0.f, 0.f}; return z; }

// ---------------- setup: Mbt[y][x] = sum_o Wq'[o][x] Wk'[o][y] (bf16), u[y]
__global__ void pam_setup(const float* __restrict__ Wq, const float* __restrict__ bq,
                          const float* __restrict__ gq, const float* __restrict__ betaq,
                          const float* __restrict__ mq, const float* __restrict__ vq,
                          const float* __restrict__ Wk, const float* __restrict__ gk,
                          const float* __restrict__ vk,
                          short* __restrict__ Mbt, float* __restrict__ u) {
  int blk = blockIdx.x, tid = threadIdx.x;
  if (blk < 16) {
    int entry = blk * 256 + tid;
    int y = entry >> 6, x = entry & 63;
    float acc = 0.f;
    for (int o = 0; o < 64; ++o) {
      float sq = gq[o] * rsqrtf(vq[o] + 1e-5f);
      float sk = gk[o] * rsqrtf(vk[o] + 1e-5f);
      acc += Wq[o * 64 + x] * sq * Wk[o * 64 + y] * sk;
    }
    Mbt[y * 64 + x] = (short)f2bf(acc);
  } else if (tid < 64) {
    int y = tid;
    float acc = 0.f;
    for (int o = 0; o < 64; ++o) {
      float sq = gq[o] * rsqrtf(vq[o] + 1e-5f);
      float sk = gk[o] * rsqrtf(vk[o] + 1e-5f);
      float bqq = bq[o] * sq + betaq[o] - mq[o] * sq;
      acc += bqq * Wk[o * 64 + y] * sk;
    }
    u[y] = acc;
  }
}

// ---------------- main: one block per (b,h), both directions; grid 1024
__global__ __launch_bounds__(512, 4) void pam_main(
    const float* __restrict__ fl, const float* __restrict__ fr,
    const short* __restrict__ Mbt, const float* __restrict__ uvec,
    float* __restrict__ out) {
  extern __shared__ __align__(16) char sm[];
  char* Xt  = sm;                     // [256 pos][64 c] bf16 swizzled (re-staged per era)
  char* Xn0 = sm + 32768;             // 2 x 8KB V-tile double buffer
  char* Pt  = sm + 49152;             // 8 waves x [32 w][32 v] bf16 chunk (64B rows);
                                      //   doubles as Q~ scratch during eras (Xn0-disjoint)
  float* tl = (float*)(sm + 65536);   // [2][256] t/64
  float* Db = (float*)(sm + 67584);   // [8][32] 1/D

  const int tid  = threadIdx.x;
  const int lane = tid & 63;
  const int wave = tid >> 6;
  const int l15  = lane & 15;
  const int g    = lane >> 4;
  const int bb   = blockIdx.x >> 7;
  const int hh   = blockIdx.x & 127;
  const int rowOff = hh * 256;
  const int base_b = bb * 64;
  const int w0   = wave * 32;

  char* scr = Pt + wave * 2048;       // per-wave Q~ scratch [32][32] bf16 (era phase only)
  char* Ptw = Pt + wave * 2048;       // per-wave P chunk    [32][32] bf16 (attend phase)

  // stage one f32 tensor slab -> Xt bf16 [pos][chan]
  auto stageX = [&](const float* src) {
    #pragma unroll
    for (int it = 0; it < 8; ++it) {
      int unit = it * 512 + tid;        // 0..4095
      int cq = unit >> 8;               // channel quad 0..15
      int p  = unit & 255;              // position
      const float* s = src + (size_t)(base_b + cq * 4) * HW_ + rowOff + p;
      float v0 = s[0], v1 = s[HW_], v2 = s[2 * HW_], v3 = s[3 * HW_];
      short4v pk;
      pk[0] = (short)f2bf(v0); pk[1] = (short)f2bf(v1);
      pk[2] = (short)f2bf(v2); pk[3] = (short)f2bf(v3);
      *(short4v*)swz(Xt, p, cq * 8) = pk;
    }
  };

  // t[p]/64 = (u . Xt[p][:]) / 64   (threads 0..255)
  auto tdot = [&](int p) -> float {
    float acc = 0.f;
    #pragma unroll
    for (int j = 0; j < 8; ++j) {
      short8 xv = *(const short8*)swz(Xt, p, j * 16);
      #pragma unroll
      for (int e = 0; e < 8; ++e)
        acc = fmaf(bf2f(xv[e]), uvec[j * 8 + e], acc);
    }
    return acc * 0.015625f;
  };

  // Q~ = M^T Xq : per-wave 64e x 32w, result as S-GEMM B-fragments in regs
  auto qtilde = [&](short8 (&dst)[2][2]) {
    short8 xq[2][2];
    #pragma unroll
    for (int nj = 0; nj < 2; ++nj)
      #pragma unroll
      for (int kk = 0; kk < 2; ++kk)
        xq[nj][kk] = *(const short8*)swz(Xt, w0 + nj * 16 + l15, (kk * 32 + 8 * g) * 2);
    #pragma unroll
    for (int h = 0; h < 2; ++h) {
      f32x4 qa[2][2];
      #pragma unroll
      for (int qq = 0; qq < 2; ++qq) { qa[qq][0] = zero4(); qa[qq][1] = zero4(); }
      #pragma unroll
      for (int qq = 0; qq < 2; ++qq)
        #pragma unroll
        for (int kk = 0; kk < 2; ++kk) {
          short8 am = *(const short8*)(Mbt + ((2 * h + qq) * 16 + l15) * 64 + kk * 32 + 8 * g);
          qa[qq][0] = __builtin_amdgcn_mfma_f32_16x16x32_bf16(am, xq[0][kk], qa[qq][0], 0, 0, 0);
          qa[qq][1] = __builtin_amdgcn_mfma_f32_16x16x32_bf16(am, xq[1][kk], qa[qq][1], 0, 0, 0);
        }
      #pragma unroll
      for (int qq = 0; qq < 2; ++qq)
        #pragma unroll
        for (int nj = 0; nj < 2; ++nj) {
          short4v p4;
          p4[0] = (short)f2bf(qa[qq][nj][0]); p4[1] = (short)f2bf(qa[qq][nj][1]);
          p4[2] = (short)f2bf(qa[qq][nj][2]); p4[3] = (short)f2bf(qa[qq][nj][3]);
          *(short4v*)swzQ(scr, nj * 16 + l15, qq * 32 + 8 * g) = p4;
        }
      #pragma unroll
      for (int nj = 0; nj < 2; ++nj)
        dst[nj][h] = *(const short8*)swzQ(scr, nj * 16 + l15, 16 * g);
    }
  };

  // one attention direction; Xt must hold the kv-side tensor
  auto attend = [&](const float* srcv, short8 (&bq_)[2][2], const float* tp,
                    float* outp) {
    f32x4 acc_o[2][4];
    #pragma unroll
    for (int i = 0; i < 2; ++i)
      #pragma unroll
      for (int j = 0; j < 4; ++j) acc_o[i][j] = zero4();
    float dacc0 = 0.f, dacc1 = 0.f;

    const int vc = tid >> 3;
    const int v8 = (tid & 7) * 8;
    const float* vbase = srcv + (size_t)(base_b + vc) * HW_ + rowOff + v8;
    f32x4 A0 = *(const f32x4*)vbase;
    f32x4 A1 = *(const f32x4*)(vbase + 4);
    auto stV = [&](char* buf) {
      short8 pk;
      pk[0] = (short)f2bf(A0[0]); pk[1] = (short)f2bf(A0[1]);
      pk[2] = (short)f2bf(A0[2]); pk[3] = (short)f2bf(A0[3]);
      pk[4] = (short)f2bf(A1[0]); pk[5] = (short)f2bf(A1[1]);
      pk[6] = (short)f2bf(A1[2]); pk[7] = (short)f2bf(A1[3]);
      *(short8*)swz(buf, vc, v8 * 2) = pk;
    };
    stV(Xn0);                                      // tile 0 -> buf 0
    A0 = *(const f32x4*)(vbase + 64);
    A1 = *(const f32x4*)(vbase + 68);
    __syncthreads();                               // buf0 visible

    for (int vt = 0; vt < 4; ++vt) {
      if (vt < 3) stV(Xn0 + ((vt + 1) & 1) * 8192);
      if (vt < 2) {
        A0 = *(const f32x4*)(vbase + (vt + 2) * 64);
        A1 = *(const f32x4*)(vbase + (vt + 2) * 64 + 4);
      }
      char* XnB = Xn0 + (vt & 1) * 8192;
      #pragma unroll
      for (int h = 0; h < 2; ++h) {
        short8 af[2][2];
        #pragma unroll
        for (int qq = 0; qq < 2; ++qq)
          #pragma unroll
          for (int kk = 0; kk < 2; ++kk)
            af[qq][kk] = *(const short8*)swz(Xt, vt * 64 + (2 * h + qq) * 16 + l15,
                                             (kk * 32 + 8 * g) * 2);
        #pragma unroll
        for (int nj = 0; nj < 2; ++nj) {
          f32x4 s0 = zero4(), s1 = zero4();
          #pragma unroll
          for (int kk = 0; kk < 2; ++kk) {
            s0 = __builtin_amdgcn_mfma_f32_16x16x32_bf16(af[0][kk], bq_[nj][kk], s0, 0, 0, 0);
            s1 = __builtin_amdgcn_mfma_f32_16x16x32_bf16(af[1][kk], bq_[nj][kk], s1, 0, 0, 0);
          }
          float dl = 0.f;
          #pragma unroll
          for (int qq = 0; qq < 2; ++qq) {
            f32x4 sv = qq ? s1 : s0;
            f32x4 tr = *(const f32x4*)(tp + vt * 64 + (2 * h + qq) * 16 + 4 * g);
            f32x4 pv;
            #pragma unroll
            for (int r = 0; r < 4; ++r)
              pv[r] = __expf(fmaf(sv[r], 0.015625f, tr[r]));
            dl += pv[0] + pv[1] + pv[2] + pv[3];
            short4v p4;
            p4[0] = (short)f2bf(pv[0]); p4[1] = (short)f2bf(pv[1]);
            p4[2] = (short)f2bf(pv[2]); p4[3] = (short)f2bf(pv[3]);
            *(short4v*)swzQ(Ptw, nj * 16 + l15, qq * 32 + 8 * g) = p4;
          }
          if (nj == 0) dacc0 += dl; else dacc1 += dl;
        }
        // PV for v-half h
        short8 pa0 = *(const short8*)swzQ(Ptw, l15,      16 * g);
        short8 pa1 = *(const short8*)swzQ(Ptw, 16 + l15, 16 * g);
        #pragma unroll
        for (int nj2 = 0; nj2 < 4; ++nj2) {
          short8 xb = *(const short8*)swz(XnB, nj2 * 16 + l15, h * 64 + 16 * g);
          acc_o[0][nj2] = __builtin_amdgcn_mfma_f32_16x16x32_bf16(pa0, xb, acc_o[0][nj2], 0, 0, 0);
          acc_o[1][nj2] = __builtin_amdgcn_mfma_f32_16x16x32_bf16(pa1, xb, acc_o[1][nj2], 0, 0, 0);
        }
      }
      __syncthreads();                             // next buf visible / this buf free
    }

    // D reduce + epilogue
    dacc0 += __shfl_xor(dacc0, 16); dacc0 += __shfl_xor(dacc0, 32);
    dacc1 += __shfl_xor(dacc1, 16); dacc1 += __shfl_xor(dacc1, 32);
    if (lane < 16) {
      Db[wave * 32 + lane]      = __builtin_amdgcn_rcpf(dacc0);
      Db[wave * 32 + 16 + lane] = __builtin_amdgcn_rcpf(dacc1);
    }
    #pragma unroll
    for (int mi2 = 0; mi2 < 2; ++mi2) {
      f32x4 rd = *(const f32x4*)(Db + wave * 32 + mi2 * 16 + 4 * g);
      #pragma unroll
      for (int nj2 = 0; nj2 < 4; ++nj2) {
        int c = nj2 * 16 + l15;
        f32x4 v;
        v[0] = acc_o[mi2][nj2][0] * rd[0];
        v[1] = acc_o[mi2][nj2][1] * rd[1];
        v[2] = acc_o[mi2][nj2][2] * rd[2];
        v[3] = acc_o[mi2][nj2][3] * rd[3];
        *(f32x4*)(outp + (size_t)c * HW_ + w0 + mi2 * 16 + 4 * g) = v;
      }
    }
  };

  short8 bqf[2][2][2];   // [at][nj][kk]

  // era 1: XL staged
  stageX(fl);
  __syncthreads();
  if (tid < 256) tl[256 + tid] = tdot(tid);   // t for at=1 (kv = XL)
  qtilde(bqf[0]);                             // queries of at=0 come from XL
  __syncthreads();
  // era 2: XR staged
  stageX(fr);
  __syncthreads();
  if (tid < 256) tl[tid] = tdot(tid);         // t for at=0 (kv = XR)
  qtilde(bqf[1]);
  __syncthreads();
  // at = 0: kv = XR (staged), V from fr
  attend(fr, bqf[0], tl, out + (size_t)base_b * HW_ + rowOff);
  // era 3: XL re-staged (L3-resident re-read)
  stageX(fl);
  __syncthreads();
  // at = 1: kv = XL, V from fl
  attend(fl, bqf[1], tl + 256, out + OUTHALF + (size_t)base_b * HW_ + rowOff);
}

extern "C" void kernel_launch(void* const* d_in, const int* in_sizes, int n_in,
                              void* d_out, int out_size, void* d_ws, size_t ws_size,
                              hipStream_t stream) {
  (void)in_sizes; (void)n_in; (void)out_size; (void)ws_size;
  const float* fl    = (const float*)d_in[0];
  const float* fr    = (const float*)d_in[1];
  const float* Wq    = (const float*)d_in[2];
  const float* bq    = (const float*)d_in[3];
  const float* gq    = (const float*)d_in[4];
  const float* betaq = (const float*)d_in[5];
  const float* mq    = (const float*)d_in[6];
  const float* vq    = (const float*)d_in[7];
  const float* Wk    = (const float*)d_in[8];
  const float* gk    = (const float*)d_in[10];
  const float* vk    = (const float*)d_in[13];
  short* Mbt = (short*)d_ws;
  float* u   = (float*)((char*)d_ws + 8192);
  float* out = (float*)d_out;

  hipFuncSetAttribute((const void*)pam_main,
                      hipFuncAttributeMaxDynamicSharedMemorySize, SMEM_BYTES);
  pam_setup<<<17, 256, 0, stream>>>(Wq, bq, gq, betaq, mq, vq, Wk, gk, vk, Mbt, u);
  pam_main<<<1024, 512, SMEM_BYTES, stream>>>(fl, fr, Mbt, u, out);
}

// Round 5
// 127.697 us; speedup vs baseline: 1.4383x; 1.4383x over previous
//
#include <hip/hip_runtime.h>

// Problem constants (B=8, C=64, H=128, W=256)
#define HW_ 32768          // H*W
#define OUTHALF 16777216ULL
#define SMEM_BYTES 117760

typedef short short8  __attribute__((ext_vector_type(8)));
typedef short short4v __attribute__((ext_vector_type(4)));
typedef float f32x4   __attribute__((ext_vector_type(4)));

__device__ __forceinline__ unsigned short f2bf(float f) {
  unsigned u = __builtin_bit_cast(unsigned, f);
  u += 0x7fffu + ((u >> 16) & 1u);          // RNE; inputs are finite
  return (unsigned short)(u >> 16);
}
__device__ __forceinline__ float bf2f(short s) {
  unsigned u = ((unsigned)(unsigned short)s) << 16;
  return __builtin_bit_cast(float, u);
}
__device__ __forceinline__ char* swz(char* base, int row, int colByte) {
  // 128-byte rows; XOR-swizzle kills stride-128 bank conflicts (R1-proven)
  return base + row * 128 + (colByte ^ ((row & 7) << 4));
}
__device__ __forceinline__ f32x4 zero4() { f32x4 z = {0.f, 0.f, 0.f, 0.f}; return z; }

// ---------------- setup: Mbt[d][e] = sum_o Wq'[o][e] Wk'[o][d] (bf16), u[y]
__global__ void pam_setup(const float* __restrict__ Wq, const float* __restrict__ bq,
                          const float* __restrict__ gq, const float* __restrict__ betaq,
                          const float* __restrict__ mq, const float* __restrict__ vq,
                          const float* __restrict__ Wk, const float* __restrict__ gk,
                          const float* __restrict__ vk,
                          short* __restrict__ Mbt, float* __restrict__ u) {
  int blk = blockIdx.x, tid = threadIdx.x;
  if (blk < 16) {
    int entry = blk * 256 + tid;
    int y = entry >> 6, x = entry & 63;
    float acc = 0.f;
    for (int o = 0; o < 64; ++o) {
      float sq = gq[o] * rsqrtf(vq[o] + 1e-5f);
      float sk = gk[o] * rsqrtf(vk[o] + 1e-5f);
      acc += Wq[o * 64 + x] * sq * Wk[o * 64 + y] * sk;
    }
    Mbt[y * 64 + x] = (short)f2bf(acc);
  } else if (tid < 64) {
    int y = tid;
    float acc = 0.f;
    for (int o = 0; o < 64; ++o) {
      float sq = gq[o] * rsqrtf(vq[o] + 1e-5f);
      float sk = gk[o] * rsqrtf(vk[o] + 1e-5f);
      float bqq = bq[o] * sq + betaq[o] - mq[o] * sq;
      acc += bqq * Wk[o * 64 + y] * sk;
    }
    u[y] = acc;
  }
}

// ---------------- main: one block per (b,h), both directions; grid 1024 x 1024 threads
__global__ __launch_bounds__(1024, 4) void pam_main(
    const float* __restrict__ fl, const float* __restrict__ fr,
    const short* __restrict__ Mbt, const float* __restrict__ uvec,
    float* __restrict__ out) {
  extern __shared__ __align__(16) char sm[];
  char* XLt = sm;                     // [256 pos][64 c] bf16 swizzled
  char* XRt = sm + 32768;
  char* Xn0 = sm + 65536;             // 2 x 8KB V-tile double buffer [64 c][64 v]
  char* Pt  = sm + 81920;             // 16 waves x [16 w][64 v] bf16 (128B rows);
                                      //   also per-wave Q~ scratch outside vt loop
  float* tl = (float*)(sm + 114688);  // [2][256] t/64
  float* Db = (float*)(sm + 116736);  // [16][16] 1/D

  const int tid  = threadIdx.x;
  const int lane = tid & 63;
  const int wave = tid >> 6;          // 0..15
  const int l15  = lane & 15;
  const int g    = lane >> 4;
  const int bb   = blockIdx.x >> 7;
  const int hh   = blockIdx.x & 127;
  const int rowOff = hh * 256;
  const int base_b = bb * 64;
  const int w0   = wave * 16;         // this wave's 16 query rows

  char* Ptw = Pt + wave * 2048;

  // ---- stage XLt + XRt (f32 global -> bf16 LDS, [pos][chan]) ----
  #pragma unroll
  for (int it = 0; it < 8; ++it) {
    int unit = it * 1024 + tid;       // 0..8191
    int tensor = unit >> 12;
    int rem = unit & 4095;
    int cq = rem >> 8;                // channel quad 0..15
    int p  = rem & 255;               // position
    const float* s = (tensor ? fr : fl) + (size_t)(base_b + cq * 4) * HW_ + rowOff + p;
    float v0 = s[0], v1 = s[HW_], v2 = s[2 * HW_], v3 = s[3 * HW_];
    short4v pk;
    pk[0] = (short)f2bf(v0); pk[1] = (short)f2bf(v1);
    pk[2] = (short)f2bf(v2); pk[3] = (short)f2bf(v3);
    *(short4v*)swz(tensor ? XRt : XLt, p, cq * 8) = pk;
  }
  __syncthreads();

  // ---- t[p]/64 = (u . X_kv[p][:]) / 64 ; tl[0] from XRt (at=0), tl[1] from XLt ----
  if (tid < 512) {
    int sel = tid >> 8, p = tid & 255;
    char* xt = sel ? XLt : XRt;
    float acc = 0.f;
    #pragma unroll
    for (int j = 0; j < 8; ++j) {
      short8 xv = *(const short8*)swz(xt, p, j * 16);
      #pragma unroll
      for (int e = 0; e < 8; ++e)
        acc = fmaf(bf2f(xv[e]), uvec[j * 8 + e], acc);
    }
    tl[sel * 256 + p] = acc * 0.015625f;
  }

  #pragma unroll 1
  for (int at = 0; at < 2; ++at) {
    char* Xq  = at ? XRt : XLt;       // query side
    char* Xkv = at ? XLt : XRt;       // key/value side (S-GEMM A operand)
    const float* skv = at ? fl : fr;  // V source (global re-read, L2/L3-resident)
    const float* tp  = tl + at * 256;
    float* outp = out + (at ? OUTHALF : 0) + (size_t)base_b * HW_ + rowOff;

    // ---- Q~ = M^T Xq for this wave's 16 rows -> B-fragments in regs ----
    short8 bq_[2];
    {
      short8 xb_[2];
      #pragma unroll
      for (int kk = 0; kk < 2; ++kk)
        xb_[kk] = *(const short8*)swz(Xq, w0 + l15, (kk * 32 + 8 * g) * 2);
      #pragma unroll
      for (int mi = 0; mi < 4; ++mi) {
        f32x4 q = zero4();
        #pragma unroll
        for (int kk = 0; kk < 2; ++kk) {
          short8 am = *(const short8*)(Mbt + (mi * 16 + l15) * 64 + kk * 32 + 8 * g);
          q = __builtin_amdgcn_mfma_f32_16x16x32_bf16(am, xb_[kk], q, 0, 0, 0);
        }
        // lane holds Q~[d = mi*16+4g+r][w = w0+l15] -> scratch [16 w][64 d]
        short4v p4;
        p4[0] = (short)f2bf(q[0]); p4[1] = (short)f2bf(q[1]);
        p4[2] = (short)f2bf(q[2]); p4[3] = (short)f2bf(q[3]);
        *(short4v*)swz(Ptw, l15, mi * 32 + 8 * g) = p4;
      }
      #pragma unroll
      for (int kk = 0; kk < 2; ++kk)
        bq_[kk] = *(const short8*)swz(Ptw, l15, kk * 64 + 16 * g);
    }

    // ---- per-direction accumulators ----
    f32x4 acc_o[4];
    #pragma unroll
    for (int j = 0; j < 4; ++j) acc_o[j] = zero4();
    float dacc = 0.f;

    // ---- V-tile prologue (tile 0 -> buf 0) ----
    const int vc = tid >> 4;          // 0..63 channel
    const int v4 = (tid & 15) * 4;    // 4 positions
    const float* vbase = skv + (size_t)(base_b + vc) * HW_ + rowOff + v4;
    f32x4 A0 = *(const f32x4*)vbase;
    {
      short4v pk;
      pk[0] = (short)f2bf(A0[0]); pk[1] = (short)f2bf(A0[1]);
      pk[2] = (short)f2bf(A0[2]); pk[3] = (short)f2bf(A0[3]);
      *(short4v*)swz(Xn0, vc, v4 * 2) = pk;
    }
    A0 = *(const f32x4*)(vbase + 64);
    __syncthreads();                  // buf0 + (at=0: tl) visible

    for (int vt = 0; vt < 4; ++vt) {
      // stage next V tile into the other buffer (overlaps compute)
      if (vt < 3) {
        short4v pk;
        pk[0] = (short)f2bf(A0[0]); pk[1] = (short)f2bf(A0[1]);
        pk[2] = (short)f2bf(A0[2]); pk[3] = (short)f2bf(A0[3]);
        *(short4v*)swz(Xn0 + ((vt + 1) & 1) * 8192, vc, v4 * 2) = pk;
      }
      if (vt < 2) A0 = *(const f32x4*)(vbase + (vt + 2) * 64);
      char* XnB = Xn0 + (vt & 1) * 8192;

      // ---- S-GEMM: S_T[vl][w] = sum_d Xkv[vl][d] Q~[d][w] ----
      f32x4 accs[4];
      #pragma unroll
      for (int mi = 0; mi < 4; ++mi) {
        accs[mi] = zero4();
        #pragma unroll
        for (int kk = 0; kk < 2; ++kk) {
          short8 af = *(const short8*)swz(Xkv, vt * 64 + mi * 16 + l15,
                                          (kk * 32 + 8 * g) * 2);
          accs[mi] = __builtin_amdgcn_mfma_f32_16x16x32_bf16(af, bq_[kk], accs[mi], 0, 0, 0);
        }
      }
      // ---- exp + P -> per-wave LDS + D accumulation ----
      #pragma unroll
      for (int mi = 0; mi < 4; ++mi) {
        f32x4 tr = *(const f32x4*)(tp + vt * 64 + mi * 16 + 4 * g);
        f32x4 pv;
        #pragma unroll
        for (int r = 0; r < 4; ++r)
          pv[r] = __expf(fmaf(accs[mi][r], 0.015625f, tr[r]));
        dacc += pv[0] + pv[1] + pv[2] + pv[3];
        short4v p4;
        p4[0] = (short)f2bf(pv[0]); p4[1] = (short)f2bf(pv[1]);
        p4[2] = (short)f2bf(pv[2]); p4[3] = (short)f2bf(pv[3]);
        *(short4v*)swz(Ptw, l15, mi * 32 + 8 * g) = p4;
      }
      // ---- PV-GEMM: O[w][c] += sum_v P[w][v] V[c][v] ----
      #pragma unroll
      for (int kk = 0; kk < 2; ++kk) {
        short8 pa = *(const short8*)swz(Ptw, l15, kk * 64 + 16 * g);
        #pragma unroll
        for (int nj2 = 0; nj2 < 4; ++nj2) {
          short8 xb = *(const short8*)swz(XnB, nj2 * 16 + l15, (kk * 32 + 8 * g) * 2);
          acc_o[nj2] = __builtin_amdgcn_mfma_f32_16x16x32_bf16(pa, xb, acc_o[nj2], 0, 0, 0);
        }
      }
      __syncthreads();                // next buf visible / this buf free
    } // vt

    // ---- D reduce (across g groups) + epilogue ----
    dacc += __shfl_xor(dacc, 16); dacc += __shfl_xor(dacc, 32);
    if (lane < 16) Db[wave * 16 + lane] = __builtin_amdgcn_rcpf(dacc);
    f32x4 rd = *(const f32x4*)(Db + wave * 16 + 4 * g);
    #pragma unroll
    for (int nj2 = 0; nj2 < 4; ++nj2) {
      int c = nj2 * 16 + l15;
      f32x4 v;
      v[0] = acc_o[nj2][0] * rd[0];
      v[1] = acc_o[nj2][1] * rd[1];
      v[2] = acc_o[nj2][2] * rd[2];
      v[3] = acc_o[nj2][3] * rd[3];
      *(f32x4*)(outp + (size_t)c * HW_ + w0 + 4 * g) = v;
    }
  } // at
}

extern "C" void kernel_launch(void* const* d_in, const int* in_sizes, int n_in,
                              void* d_out, int out_size, void* d_ws, size_t ws_size,
                              hipStream_t stream) {
  (void)in_sizes; (void)n_in; (void)out_size; (void)ws_size;
  const float* fl    = (const float*)d_in[0];
  const float* fr    = (const float*)d_in[1];
  const float* Wq    = (const float*)d_in[2];
  const float* bq    = (const float*)d_in[3];
  const float* gq    = (const float*)d_in[4];
  const float* betaq = (const float*)d_in[5];
  const float* mq    = (const float*)d_in[6];
  const float* vq    = (const float*)d_in[7];
  const float* Wk    = (const float*)d_in[8];
  const float* gk    = (const float*)d_in[10];
  const float* vk    = (const float*)d_in[13];
  short* Mbt = (short*)d_ws;
  float* u   = (float*)((char*)d_ws + 8192);
  float* out = (float*)d_out;

  hipFuncSetAttribute((const void*)pam_main,
                      hipFuncAttributeMaxDynamicSharedMemorySize, SMEM_BYTES);
  pam_setup<<<17, 256, 0, stream>>>(Wq, bq, gq, betaq, mq, vq, Wk, gk, vk, Mbt, u);
  pam_main<<<1024, 1024, SMEM_BYTES, stream>>>(fl, fr, Mbt, u, out);
}